// Round 10
// baseline (70.464 us; speedup 1.0000x reference)
//
#include <hip/hip_runtime.h>
#include <hip/hip_bf16.h>
#include <math.h>

// Problem constants
#define BATCH 1024
#define X_DIM 32
#define U_DIM 8
#define PHI 128
#define HID 128

// 128B lines needed per triangle orientation: sum_r (r/32 + 1) = 320 = 40*8
#define NLINE 320

typedef float f4 __attribute__((ext_vector_type(4)));

__device__ __forceinline__ float fast_tanh(float x) {
    return 1.0f - 2.0f / (__expf(2.0f * x) + 1.0f);
}

// ---------------------------------------------------------------------------
// R9 structure (best: 70.2us) + ONE change: LINE-granular teams. Instead of
// 64 lanes gathering 64 packed 16B chunks (row fragments -> 10-16 partially
// consumed, unaligned lines per instruction), each iteration assigns 8 teams
// of 8 lanes to 8 whole 128B lines of the packed line list: team g takes
// line i*8+g, its 8 lanes read contiguous 16B each. Every VMEM instruction
// is exactly 8 fully-dense aligned lines (R2's request shape, which measured
// 89% of achievable BW, vs 77% for the chunk gather). 40 iters = 320 lines.
// Everything else verbatim from R9: mixed lower/upper orientation by wave
// parity (channel balance), rolling 4-deep offset prefetch (LDS out of the
// VMEM address path), NT loads, same operand reads / weights / reduction.
//   lower weights: q<r -> 1, q==r -> 0.5, q>r -> 0   (ek = 4c+k-r)
//   upper weights: q>r -> 1, q==r -> 0.5, q<r -> 0   (ek = r-4c-k)
// ---------------------------------------------------------------------------
__global__ __launch_bounds__(512) void fused_kernel(
    const float* __restrict__ x,
    const float* __restrict__ Q,
    const float* __restrict__ L,
    const float* __restrict__ W1, const float* __restrict__ b1,
    const float* __restrict__ W2, const float* __restrict__ b2,
    const float* __restrict__ W3, const float* __restrict__ b3,
    const float* __restrict__ W4, const float* __restrict__ b4,
    const float* __restrict__ logSigEps,
    float* __restrict__ mu_out,   // 8192 = (B,U,1)
    float* __restrict__ sig_out)  // 65536 = (B,U,U)
{
    const int b = blockIdx.x;
    const int t = threadIdx.x;     // 0..511

    __shared__ float sx[X_DIM];
    __shared__ float h[HID];
    __shared__ alignas(16) float s_phi[PHI];
    __shared__ alignas(16) float s_Q[U_DIM * PHI];   // 4KB
    __shared__ unsigned short s_tabL[NLINE];         // 640B: packed line offsets
    __shared__ unsigned short s_tabU[NLINE];         // 640B

    // preload Q (1024 floats) with all 512 threads, and x with the first 32
    {
        const float2* Qg = (const float2*)(Q + (size_t)b * (U_DIM * PHI));
        ((float2*)s_Q)[t] = Qg[t];
    }
    if (t < X_DIM) sx[t] = x[b * X_DIM + t];

    // build both LINE tables (identical for all blocks; once per block).
    // lower: row r needs line-cols lc = 0..m (m = r>>5), base = r + 16m(m-1) + (r&31)m
    // upper: row r needs line-cols lc = m..3,  base = 4r - (16m(m-1) + (r&31)m)
    // entry = byte offset of line = r*512 + lc*128 (fits u16: max 65408)
    if (t < 256) {
        const int r = t & 127;
        const int m = r >> 5;
        const int s = 16 * m * (m - 1) + (r & 31) * m;
        if (t < 128) {
            const int base = r + s;
            for (int lc = 0; lc <= m; ++lc)
                s_tabL[base + lc] = (unsigned short)((r << 9) | (lc << 7));
        } else {
            const int base = 4 * r - s;
            for (int lc = m; lc < 4; ++lc)
                s_tabU[base + (lc - m)] = (unsigned short)((r << 9) | (lc << 7));
        }
    }
    __syncthreads();

    // ---- Phase 1: MLP on threads 0..127 ----
    float acc;
    if (t < HID) {
        acc = b1[t];
#pragma unroll
        for (int k = 0; k < X_DIM; ++k) acc += sx[k] * W1[k * HID + t];
        h[t] = fast_tanh(acc);
    }
    __syncthreads();
    if (t < HID) {
        acc = b2[t];
#pragma unroll 8
        for (int k = 0; k < HID; ++k) acc += h[k] * W2[k * HID + t];
        acc = fast_tanh(acc);
    }
    __syncthreads();
    if (t < HID) h[t] = acc;
    __syncthreads();
    if (t < HID) {
        acc = b3[t];
#pragma unroll 8
        for (int k = 0; k < HID; ++k) acc += h[k] * W3[k * HID + t];
        acc = fast_tanh(acc);
    }
    __syncthreads();
    if (t < HID) h[t] = acc;
    __syncthreads();
    if (t < HID) {
        acc = b4[t];
#pragma unroll 8
        for (int k = 0; k < HID; ++k) acc += h[k] * W4[k * HID + t];
        s_phi[t] = acc;
    }
    __syncthreads();

    // ---- Phase 2: per-wave packed-LINE stream, 8 lanes per line ----
    const int u  = t >> 6;         // wave id = tile id, 0..7
    const int l  = t & 63;         // lane
    const int g  = l >> 3;         // team 0..7 -> which line this iteration
    const int tl = l & 7;          // lane within team -> 16B slot in the line
    const bool isUp = (u & 1) != 0;
    const int  dk   = isUp ? -1 : 1;

    const unsigned short* __restrict__ tab = isUp ? s_tabU : s_tabL;

    const char* __restrict__ Lbase =
        (const char*)(L + ((size_t)(b * U_DIM + u)) * (PHI * PHI));
    const float* __restrict__ Qu = s_Q + u * PHI;
    const f4* __restrict__ s_phi4 = (const f4*)s_phi;
    const f4* __restrict__ Qu4 = (const f4*)Qu;

    const int tl16 = tl << 4;

    // rolling 4-deep prefetch of this lane's line offsets (+lane slot): the
    // global-load address is in a VGPR 4 iterations before use.
    int offs[4];
#pragma unroll
    for (int k = 0; k < 4; ++k) offs[k] = (int)tab[(k << 3) + g] + tl16;

    float accm = 0.0f, accf = 0.0f;
#pragma unroll
    for (int i = 0; i < 40; ++i) {
        const int off = offs[i & 3];                       // static after unroll
        if (i + 4 < 40) offs[i & 3] = (int)tab[((i + 4) << 3) + g] + tl16;

        const f4 v = __builtin_nontemporal_load((const f4*)(Lbase + off));
        const int r = off >> 9;
        const int c = (off >> 4) & 31;
        const float phir = s_phi[r];
        const float Qr   = Qu[r];
        const f4 ph = s_phi4[c];
        const f4 Qv = Qu4[c];
        // ek for k=0; advance by dk per element. weight: ek<0 ->1, ==0 ->0.5, >0 ->0
        int ek = isUp ? (r - 4 * c) : (4 * c - r);

        {
            const float w = (ek < 0) ? 1.0f : ((ek == 0) ? 0.5f : 0.0f);
            const float tv = w * v.x;
            accm += tv * (Qr * ph.x + Qv.x * phir);
            accf += tv * (phir * ph.x);
        }
        ek += dk;
        {
            const float w = (ek < 0) ? 1.0f : ((ek == 0) ? 0.5f : 0.0f);
            const float tv = w * v.y;
            accm += tv * (Qr * ph.y + Qv.y * phir);
            accf += tv * (phir * ph.y);
        }
        ek += dk;
        {
            const float w = (ek < 0) ? 1.0f : ((ek == 0) ? 0.5f : 0.0f);
            const float tv = w * v.z;
            accm += tv * (Qr * ph.z + Qv.z * phir);
            accf += tv * (phir * ph.z);
        }
        ek += dk;
        {
            const float w = (ek < 0) ? 1.0f : ((ek == 0) ? 0.5f : 0.0f);
            const float tv = w * v.w;
            accm += tv * (Qr * ph.w + Qv.w * phir);
            accf += tv * (phir * ph.w);
        }
    }

    // intra-wave butterfly reduction (64 lanes)
#pragma unroll
    for (int off = 1; off < 64; off <<= 1) {
        accm += __shfl_xor(accm, off);
        accf += __shfl_xor(accf, off);
    }

    const int bu = b * U_DIM + u;
    if (l == 0) mu_out[bu] = accm;
    if (l < U_DIM) {
        const float sf = 1.0f + 2.0f * accf;
        sig_out[(size_t)bu * U_DIM + l] = (l == u) ? __expf(logSigEps[u]) * sf : 0.0f;
    }
}

extern "C" void kernel_launch(void* const* d_in, const int* in_sizes, int n_in,
                              void* d_out, int out_size, void* d_ws, size_t ws_size,
                              hipStream_t stream)
{
    const float* x         = (const float*)d_in[0];
    const float* Q         = (const float*)d_in[1];
    const float* L         = (const float*)d_in[2];
    const float* W1        = (const float*)d_in[3];
    const float* b1        = (const float*)d_in[4];
    const float* W2        = (const float*)d_in[5];
    const float* b2        = (const float*)d_in[6];
    const float* W3        = (const float*)d_in[7];
    const float* b3        = (const float*)d_in[8];
    const float* W4        = (const float*)d_in[9];
    const float* b4        = (const float*)d_in[10];
    const float* logSigEps = (const float*)d_in[11];

    float* out     = (float*)d_out;
    float* mu_out  = out;                   // 8192
    float* sig_out = out + BATCH * U_DIM;   // 65536

    fused_kernel<<<BATCH, 512, 0, stream>>>(x, Q, L,
                                            W1, b1, W2, b2, W3, b3, W4, b4,
                                            logSigEps, mu_out, sig_out);
}